// Round 8
// baseline (27202.875 us; speedup 1.0000x reference)
//
#include <hip/hip_runtime.h>
#include <hip/hip_bf16.h>
#include <math.h>

// ---------------------------------------------------------------------------
// GMambaBlock implementation for MI355X (gfx950).
// B=16, L=1024, D=512, DI=1024, DS=16, DTR=32, FLIP_LEN=45. M = B*L = 16384.
// Tiers: A (ws >= ~197 MB): all-fp32 exact. C (>= ~85 MB): bf16 gates/gi.
// GRU: 32-block d-split, register-resident Whh, flag lockstep + watchdog.
//      Safe on any partition >= 32 CUs (CPX-proof); cannot hang (bounded spin).
// ---------------------------------------------------------------------------

#define SEQ    1024
#define NBATCH 16
#define MROWS  (NBATCH*SEQ)   // 16384
#define BUFF   8388608        // floats per [16384][512] fp32 buffer

__device__ __forceinline__ float sigm_(float x)  { return 1.f/(1.f+expf(-x)); }
__device__ __forceinline__ float silu_(float x)  { return x/(1.f+expf(-x)); }
__device__ __forceinline__ float softp_(float x) { return (x > 20.f) ? x : log1pf(expf(x)); }
__device__ __forceinline__ float bf2f_(unsigned short u) {
    return __uint_as_float(((unsigned int)u) << 16);
}

// flip row permutation: first 45 positions of each batch's L reversed
__device__ __forceinline__ int fliprow_(int g) {
    int l = g & 1023;
    int sl = (l < 45) ? (44 - l) : l;
    return (g & ~1023) | sl;
}

// W-tile LDS column swizzle (BN=128): 4-way -> 2-way (free per m136).
__device__ __forceinline__ int swzW(int col) { return col ^ (((col >> 5) & 3) << 2); }

// ---------------------------------------------------------------------------
// Generic tiled fp32 GEMM:  C[m][n] = epi( sum_k Avirt[m][k] * W[n][k] )
// BM=128, BN=128 (or 64), BK=16, 256 threads, 8x(BN/16) accumulators/thread.
// AMODE: 0 plain | 1 conv3-im2col | 2 gates fp32 | 3 flipped rows |
//        4 time-chunk rows | 5 gates mixed (fp32 silu, bf16 sigmoid)
// EPI:   0 v | 1 +bias | 2 +bias+src | 3 +bias+bias2 | 4 softplus(+bias) |
//        5 C += cw*v*(1+src f32) | 6 +bias+src[flip] | 7 C += cw*v*(1+src bf16) |
//        8 bf16(v) | 9 bf16(v+bias+bias2)
// ---------------------------------------------------------------------------
template<int AMODE, int EPI, int BN>
__global__ __launch_bounds__(256)
void gemm_k(const float* __restrict__ A, const float* __restrict__ A2,
            const float* __restrict__ W,
            const float* __restrict__ bias, const float* __restrict__ bias2,
            float* __restrict__ C, const float* __restrict__ epi_src,
            const float* __restrict__ cwp, int cwidx,
            int N, int K, int lda, int ldc, int row_off)
{
    constexpr int CT = BN / 16;            // cols per thread: 8 or 4
    __shared__ __align__(16) float As[16][132];
    __shared__ __align__(16) float Ws[16][BN + 4];

    const int tid = threadIdx.x;
    const int n0  = blockIdx.x * BN;
    const int m0  = blockIdx.y * 128;
    const int rg  = tid >> 4;   // 0..15 (8 rows each)
    const int cg  = tid & 15;   // 0..15 (CT cols each)

    const int offA = rg * 8;
    int offB0, offB1;
    if (BN == 128) { offB0 = swzW(cg*8); offB1 = swzW(cg*8 + 4); }
    else           { offB0 = cg*4;       offB1 = 0; }

    float acc[8][CT];
#pragma unroll
    for (int i = 0; i < 8; ++i)
#pragma unroll
        for (int j = 0; j < CT; ++j) acc[i][j] = 0.f;

    for (int k0 = 0; k0 < K; k0 += 16) {
        // ---- stage A tile: 128 rows x 16 k  (2 float4 per thread)
#pragma unroll
        for (int q = 0; q < 2; ++q) {
            int fl  = tid*2 + q;
            int row = fl >> 2;
            int kq  = fl & 3;
            int m   = m0 + row;
            int kk  = k0 + kq*4;
            float4 v;
            if (AMODE == 0) {
                v = *(const float4*)&A[(size_t)m*lda + kk];
            } else if (AMODE == 1) {
                int b = m >> 10, l = m & 1023;
                int tap = kk >> 9;
                int c   = kk & 511;
                int sl  = l + tap - 1;
                if (sl >= 0 && sl < SEQ)
                    v = *(const float4*)&A[((size_t)(b << 10) + sl)*512 + c];
                else
                    v = make_float4(0.f,0.f,0.f,0.f);
            } else if (AMODE == 2) {
                if (kk < 512) {
                    float4 s = *(const float4*)&A[(size_t)m*512 + kk];
                    v.x = silu_(s.x); v.y = silu_(s.y); v.z = silu_(s.z); v.w = silu_(s.w);
                } else {
                    float4 s = *(const float4*)&A2[(size_t)m*512 + (kk-512)];
                    v.x = sigm_(s.x); v.y = sigm_(s.y); v.z = sigm_(s.z); v.w = sigm_(s.w);
                }
            } else if (AMODE == 3) { // flipped x rows
                int src = fliprow_(row_off + m);
                v = *(const float4*)&A[(size_t)src*512 + kk];
            } else if (AMODE == 4) { // time-chunk rows
                int src = ((m >> 8) << 10) + row_off + (m & 255);
                v = *(const float4*)&A[(size_t)src*512 + kk];
            } else { // AMODE == 5: mixed gates (fp32 silu | bf16 sigmoid)
                if (kk < 512) {
                    float4 s = *(const float4*)&A[(size_t)m*512 + kk];
                    v.x = silu_(s.x); v.y = silu_(s.y); v.z = silu_(s.z); v.w = silu_(s.w);
                } else {
                    const unsigned short* A2b = (const unsigned short*)A2;
                    ushort4 u = *(const ushort4*)&A2b[(size_t)m*512 + (kk-512)];
                    v.x = sigm_(bf2f_(u.x)); v.y = sigm_(bf2f_(u.y));
                    v.z = sigm_(bf2f_(u.z)); v.w = sigm_(bf2f_(u.w));
                }
            }
            As[kq*4+0][row] = v.x; As[kq*4+1][row] = v.y;
            As[kq*4+2][row] = v.z; As[kq*4+3][row] = v.w;
        }
        // ---- stage W tile: BN rows x 16 k
        if (BN == 128) {
#pragma unroll
            for (int q = 0; q < 2; ++q) {
                int fl  = tid*2 + q;
                int row = fl >> 2;          // 0..127 (column in tile)
                int kq  = fl & 3;
                int n   = n0 + row;
                int kk  = k0 + kq*4;
                float4 v = *(const float4*)&W[(size_t)n*K + kk];
                int rs = swzW(row);
                Ws[kq*4+0][rs] = v.x; Ws[kq*4+1][rs] = v.y;
                Ws[kq*4+2][rs] = v.z; Ws[kq*4+3][rs] = v.w;
            }
        } else {
            int row = tid >> 2;             // 0..63
            int kq  = tid & 3;
            int n   = n0 + row;
            int kk  = k0 + kq*4;
            float4 v = *(const float4*)&W[(size_t)n*K + kk];
            Ws[kq*4+0][row] = v.x; Ws[kq*4+1][row] = v.y;
            Ws[kq*4+2][row] = v.z; Ws[kq*4+3][row] = v.w;
        }
        __syncthreads();
#pragma unroll
        for (int k = 0; k < 16; ++k) {
            float4 a0 = *(float4*)&As[k][offA];
            float4 a1 = *(float4*)&As[k][offA + 4];
            float av[8] = {a0.x,a0.y,a0.z,a0.w,a1.x,a1.y,a1.z,a1.w};
            float bv[CT];
            {
                float4 b0 = *(float4*)&Ws[k][offB0];
                bv[0]=b0.x; bv[1]=b0.y; bv[2]=b0.z; bv[3]=b0.w;
                if (BN == 128) {
                    float4 b1 = *(float4*)&Ws[k][offB1];
                    bv[4]=b1.x; bv[5]=b1.y; bv[6]=b1.z; bv[7]=b1.w;
                }
            }
#pragma unroll
            for (int i = 0; i < 8; ++i)
#pragma unroll
                for (int j = 0; j < CT; ++j)
                    acc[i][j] = fmaf(av[i], bv[j], acc[i][j]);
        }
        __syncthreads();
    }

    // ---- epilogue
    float cwv = 0.f;
    if (EPI == 5 || EPI == 7) cwv = cwp[cwidx];
#pragma unroll
    for (int i = 0; i < 8; ++i) {
        int m = m0 + rg*8 + i;
#pragma unroll
        for (int j = 0; j < CT; ++j) {
            int n = n0 + cg*CT + j;
            float v = acc[i][j];
            if (EPI == 0) {
                C[(size_t)m*ldc + n] = v;
            } else if (EPI == 1) {
                C[(size_t)m*ldc + n] = v + bias[n];
            } else if (EPI == 2) {
                C[(size_t)m*ldc + n] = v + bias[n] + epi_src[(size_t)m*512 + n];
            } else if (EPI == 3) {
                C[(size_t)m*ldc + n] = v + bias[n] + bias2[n];
            } else if (EPI == 4) {
                C[(size_t)m*ldc + n] = softp_(v + bias[n]);
            } else if (EPI == 5) {
                float g = epi_src[(size_t)m*512 + n];
                C[(size_t)m*ldc + n] += cwv * v * (1.f + g);
            } else if (EPI == 6) {
                int src = fliprow_(row_off + m);
                C[(size_t)m*ldc + n] = v + bias[n] + epi_src[(size_t)src*512 + n];
            } else if (EPI == 7) {
                float g = bf2f_(((const unsigned short*)epi_src)[(size_t)m*512 + n]);
                C[(size_t)m*ldc + n] += cwv * v * (1.f + g);
            } else if (EPI == 8) {
                ((__hip_bfloat16*)C)[(size_t)m*ldc + n] = __float2bfloat16(v);
            } else { // EPI == 9
                ((__hip_bfloat16*)C)[(size_t)m*ldc + n] =
                    __float2bfloat16(v + bias[n] + bias2[n]);
            }
        }
    }
}

// repack Wc [512][512][3] (OIH) -> [512][1536] with k = tap*512 + c
__global__ __launch_bounds__(256)
void repack_wconv_k(const float* __restrict__ Wc, float* __restrict__ out)
{
    int i = blockIdx.x*256 + threadIdx.x;    // 512*1536
    int n = i / 1536, k = i % 1536;
    int tap = k >> 9, c = k & 511;
    out[i] = Wc[(size_t)n*1536 + c*3 + tap];
}

// repack [Wsi | Wsig] -> [512][1024]
__global__ __launch_bounds__(256)
void repack_wgates_k(const float* __restrict__ Wsi, const float* __restrict__ Wsig,
                     float* __restrict__ out)
{
    int i = blockIdx.x*256 + threadIdx.x;    // 512*1024
    int n = i >> 10, k = i & 1023;
    out[i] = (k < 512) ? Wsi[(size_t)n*512 + k] : Wsig[(size_t)n*512 + k - 512];
}

// ---------------------------------------------------------------------------
// causal depthwise conv4 + bias + silu, IN PLACE on xiy chunk.
// grid (CH/1024, 8), 128 threads -> thread = (b_local, d).
// ---------------------------------------------------------------------------
__global__ __launch_bounds__(128)
void dwconv4_k(float* xiy, const float* __restrict__ w4, const float* __restrict__ cb)
{
    int bl = blockIdx.x;
    int d  = blockIdx.y*128 + threadIdx.x;
    float w0 = w4[d*4+0], w1 = w4[d*4+1], w2 = w4[d*4+2], w3 = w4[d*4+3];
    float bias = cb[d];
    float* p = xiy + (size_t)bl*SEQ*1024 + d;
    float x0 = 0.f, x1 = 0.f, x2 = 0.f;
    for (int t0 = 0; t0 < SEQ; t0 += 8) {
        float xv[8];
#pragma unroll
        for (int i = 0; i < 8; ++i) xv[i] = p[(size_t)(t0+i)*1024];
#pragma unroll
        for (int i = 0; i < 8; ++i) {
            float s = fmaf(w0,x0, fmaf(w1,x1, fmaf(w2,x2, fmaf(w3,xv[i], bias))));
            p[(size_t)(t0+i)*1024] = s / (1.f + expf(-s));
            x0 = x1; x1 = x2; x2 = xv[i];
        }
    }
}

// ---------------------------------------------------------------------------
// mamba selective scan on a CH-row chunk, fused (+ xc*Dp) * silu(z) epilogue.
// xc read from xy, y written IN PLACE. grid (CH/1024, 8), 128 threads.
// ---------------------------------------------------------------------------
__global__ __launch_bounds__(128)
void scan_k(const float* __restrict__ dtm, float* xy, const float* __restrict__ zb,
            const float* __restrict__ proj,
            const float* __restrict__ Alog, const float* __restrict__ Dpp)
{
    int bl = blockIdx.x;
    int d  = blockIdx.y*128 + threadIdx.x;
    float Ad[16];
#pragma unroll
    for (int s = 0; s < 16; ++s) Ad[s] = -expf(Alog[(size_t)d*16 + s]);
    float Dv = Dpp[d];
    float h[16];
#pragma unroll
    for (int s = 0; s < 16; ++s) h[s] = 0.f;

    __shared__ float bc[8][33];   // [i][0:16]=B, [i][16:32]=C

    for (int t0 = 0; t0 < SEQ; t0 += 8) {
        __syncthreads();
#pragma unroll
        for (int q = 0; q < 2; ++q) {
            int ii = threadIdx.x + 128*q;   // 0..255
            int i = ii >> 5, j = ii & 31;
            bc[i][j] = proj[((size_t)bl*SEQ + t0 + i)*64 + 32 + j];
        }
        __syncthreads();
        float dtv[8], xv[8], zv[8];
#pragma unroll
        for (int i = 0; i < 8; ++i) {
            size_t r = (size_t)bl*SEQ + t0 + i;
            dtv[i] = dtm[r*1024 + d];
            xv[i]  = xy [r*1024 + d];
            zv[i]  = zb [r*1024 + d];
        }
#pragma unroll
        for (int i = 0; i < 8; ++i) {
            float dtx = dtv[i]*xv[i];
            float y = 0.f;
#pragma unroll
            for (int s = 0; s < 16; ++s) {
                float dA = expf(dtv[i]*Ad[s]);
                h[s] = fmaf(dA, h[s], dtx*bc[i][s]);
                y    = fmaf(h[s], bc[i][16+s], y);
            }
            size_t r = (size_t)bl*SEQ + t0 + i;
            float sz = zv[i] / (1.f + expf(-zv[i]));
            xy[r*1024 + d] = (y + xv[i]*Dv) * sz;
        }
    }
}

// ---------------------------------------------------------------------------
// 32-block lockstep GRU over steps [t0, t1) — partition-safe (needs only 32
// co-resident blocks; CPX partition = 32 CUs). Block bx owns dims
// [bx*16, bx*16+16) for ALL 16 batches: 48 Whh rows x 512 K in registers
// (64 floats/thread, 384 threads). Per step: 32-flag barrier, stage all h
// (16x512 LDS), matvec (16 batches x 64 FMA/thread), gate phase (256 thr),
// publish. Watchdog: bounded spin -> abort latch -> terminates, never hangs.
// gi: [batch][giT][1536] (fp32 or bf16 via GI16), in-buffer step = step-t0.
// acc[b][step][512] = cw0*h. Flags monotone across chunk launches.
// ---------------------------------------------------------------------------
#define HB_STRIDE 8192   // 16*512
#define SPIN_MAX 5000000
template<bool GI16>
__global__ __launch_bounds__(384)
void gru32_k(const void* __restrict__ gi, const float* __restrict__ Whh,
             float* __restrict__ acc, const float* __restrict__ cw,
             float* __restrict__ hbuf, int* __restrict__ flags,
             int t0, int t1, int giT)
{
    const int bx    = blockIdx.x;      // 0..31 -> dims [bx*16, bx*16+16)
    const int t     = threadIdx.x;     // 0..383
    const int row_l = t % 48;          // 0..47 (gate*16 + dloc)
    const int kc    = t / 48;          // 0..7  (K chunk of 64)
    const int gate  = row_l >> 4;      // 0=r 1=z 2=n
    const int dloc  = row_l & 15;
    const int src_row = gate*512 + bx*16 + dloc;

    float w[64];
    const float* wsrc = Whh + (size_t)src_row*512 + kc*64;
#pragma unroll
    for (int i = 0; i < 64; ++i) w[i] = wsrc[i];

    __shared__ float h_lds[NBATCH][512];   // 32 KB
    __shared__ float part[NBATCH][8][48];  // 24 KB
    __shared__ int   wd;                   // watchdog latch

    if (t == 0) wd = 0;
    if (t0 == 0 && t < 256) {
        int b = t >> 4, dl = t & 15;
        __hip_atomic_store(&hbuf[b*512 + bx*16 + dl], 0.f,
                           __ATOMIC_RELAXED, __HIP_MEMORY_SCOPE_AGENT);
    }
    __syncthreads();
    if (t0 == 0 && t == 0)
        __hip_atomic_store(&flags[bx], 1, __ATOMIC_RELEASE, __HIP_MEMORY_SCOPE_AGENT);

    const float cw0 = cw[0];

    for (int step = t0; step < t1; ++step) {
        const int par = step & 1;
        if (t < 32) {
            int g = 0;
            while (__hip_atomic_load(&flags[t], __ATOMIC_ACQUIRE,
                                     __HIP_MEMORY_SCOPE_AGENT) <= step) {
                __builtin_amdgcn_s_sleep(1);
                if (++g > SPIN_MAX) { wd = 1; break; }
            }
        }
        __syncthreads();
        if (wd) break;                 // watchdog fired somewhere -> bail out
        // stage h for all batches (parity buffer of previous step)
        for (int i = t; i < NBATCH*512; i += 384)
            ((float*)h_lds)[i] =
                __hip_atomic_load(&hbuf[par*HB_STRIDE + i],
                                  __ATOMIC_RELAXED, __HIP_MEMORY_SCOPE_AGENT);
        __syncthreads();

        // matvec: partial dot over this thread's 64-wide K chunk, all batches
#pragma unroll
        for (int b = 0; b < NBATCH; ++b) {
            float p = 0.f;
            const float* hb = &h_lds[b][kc*64];
#pragma unroll
            for (int i = 0; i < 64; ++i) p = fmaf(w[i], hb[i], p);
            part[b][kc][row_l] = p;
        }
        __syncthreads();

        // gate phase: thread t<256 -> (batch, dloc)
        if (t < 256) {
            int b  = t >> 4, dl = t & 15;
            int d  = bx*16 + dl;
            float ghr = 0.f, ghz = 0.f, ghn = 0.f;
#pragma unroll
            for (int q = 0; q < 8; ++q) {
                ghr += part[b][q][dl];
                ghz += part[b][q][16 + dl];
                ghn += part[b][q][32 + dl];
            }
            size_t rowb = ((size_t)b*giT + (step - t0))*1536;
            float gr_, gz_, gn_;
            if (GI16) {
                const unsigned short* girow = (const unsigned short*)gi + rowb;
                gr_ = bf2f_(girow[d]);
                gz_ = bf2f_(girow[512+d]);
                gn_ = bf2f_(girow[1024+d]);
            } else {
                const float* girow = (const float*)gi + rowb;
                gr_ = girow[d]; gz_ = girow[512+d]; gn_ = girow[1024+d];
            }
            float r = sigm_(gr_ + ghr);
            float z = sigm_(gz_ + ghz);
            float n = tanhf(gn_ + r*ghn);
            float hprev = h_lds[b][d];
            float hnew  = fmaf(z, hprev - n, n);   // (1-z)*n + z*h
            __hip_atomic_store(&hbuf[(par^1)*HB_STRIDE + b*512 + d], hnew,
                               __ATOMIC_RELAXED, __HIP_MEMORY_SCOPE_AGENT);
            acc[((size_t)b*SEQ + step)*512 + d] = cw0 * hnew;
        }
        __syncthreads();
        if (t == 0)
            __hip_atomic_store(&flags[bx], step + 2, __ATOMIC_RELEASE,
                               __HIP_MEMORY_SCOPE_AGENT);
    }
}

// ---------------------------------------------------------------------------
extern "C" void kernel_launch(void* const* d_in, const int* in_sizes, int n_in,
                              void* d_out, int out_size, void* d_ws, size_t ws_size,
                              hipStream_t stream)
{
    // ---- input-shape guard: mismatch -> clean early-return (no OOB fault)
    if (n_in != 25 ||
        in_sizes[0]  != MROWS*512  ||   // x
        in_sizes[1]  != 3          ||   // cw
        in_sizes[8]  != 512*512*3  ||   // Wc
        in_sizes[14] != 1536*512   ||   // Wih
        in_sizes[16] != 2048*512   ||   // in_proj_W
        in_sizes[17] != 1024*4     ||   // conv_W
        in_sizes[24] != 512*1024)       // out_proj_W
        return;

    const float* x    = (const float*)d_in[0];
    const float* cw   = (const float*)d_in[1];
    const float* W1   = (const float*)d_in[2];
    const float* b1   = (const float*)d_in[3];
    const float* W2   = (const float*)d_in[4];
    const float* b2   = (const float*)d_in[5];
    const float* Wp   = (const float*)d_in[6];
    const float* bp   = (const float*)d_in[7];
    const float* Wc   = (const float*)d_in[8];
    const float* bc   = (const float*)d_in[9];
    const float* Wsig = (const float*)d_in[10];
    const float* bsig = (const float*)d_in[11];
    const float* Wsi  = (const float*)d_in[12];
    const float* bsi  = (const float*)d_in[13];
    const float* Wih  = (const float*)d_in[14];
    const float* Whh  = (const float*)d_in[15];
    const float* ipW  = (const float*)d_in[16];
    const float* cw4  = (const float*)d_in[17];
    const float* cb4  = (const float*)d_in[18];
    const float* xpW  = (const float*)d_in[19];
    const float* dtW  = (const float*)d_in[20];
    const float* dtb  = (const float*)d_in[21];
    const float* Alog = (const float*)d_in[22];
    const float* Dpf  = (const float*)d_in[23];
    const float* opW  = (const float*)d_in[24];

    float* ws = (float*)d_ws;
    const size_t WF = ws_size / 4;   // floats available
    // fixed weight/sync tail: wconv 786432 + wg 524288 + hbuf 16384 + flags 1024
    const size_t TAIL   = 786432 + 524288 + 16384 + 1024;
    const size_t NEED32 = 3*(size_t)BUFF + (size_t)MROWS*1536 + TAIL;        // ~197 MB
    const size_t NEEDC  = (size_t)BUFF + 2*4194304 + 3145728 + TAIL;         // ~85 MB
    if (WF < NEEDC) return;          // ws floor guard
    const bool tierA = (WF >= NEED32);
    dim3 blk(256);

    if (tierA) {
        // =================== Tier A: all-fp32 (~197 MB) =====================
        float* f_h1   = ws;                    // h1 raw -> h2n
        float* f_h2   = ws + BUFF;             // h2 raw -> acc
        float* f_g1   = ws + 2*(size_t)BUFF;   // g1 -> h1n
        float* f_gi   = ws + 3*(size_t)BUFF;   // gi fp32 [16384][1536]
        float* f_wconv= f_gi + (size_t)MROWS*1536;
        float* f_wg   = f_wconv + 786432;
        float* f_hbuf = f_wg + 524288;
        int*   flags  = (int*)(f_hbuf + 16384);
        const int CH  = 4096;
        float* f_xiy  = f_gi;
        float* f_z    = f_xiy + (size_t)CH*1024;
        float* f_dtc  = f_z   + (size_t)CH*1024;
        float* f_proj = f_dtc + (size_t)CH*1024;

        repack_wconv_k <<<dim3(3072), blk, 0, stream>>>(Wc, f_wconv);
        repack_wgates_k<<<dim3(2048), blk, 0, stream>>>(Wsi, Wsig, f_wg);

        gemm_k<0,2,128><<<dim3(4,128), blk, 0, stream>>>(x, nullptr, W1, b1, nullptr,
            f_h1, x, nullptr, 0, 512, 512, 512, 512, 0);
        gemm_k<3,6,128><<<dim3(4,128), blk, 0, stream>>>(x, nullptr, W2, b2, nullptr,
            f_h2, x, nullptr, 0, 512, 512, 512, 512, 0);
        gemm_k<1,1,128><<<dim3(4,128), blk, 0, stream>>>(x, nullptr, f_wconv, bc, nullptr,
            f_g1, nullptr, nullptr, 0, 512, 1536, 512, 512, 0);
        gemm_k<0,0,128><<<dim3(12,128), blk, 0, stream>>>(f_g1, nullptr, Wih, nullptr, nullptr,
            f_gi, nullptr, nullptr, 0, 1536, 512, 512, 1536, 0);
        gemm_k<2,3,128><<<dim3(4,128), blk, 0, stream>>>(f_h1, f_h1, f_wg, bsi, bsig,
            f_g1, nullptr, nullptr, 0, 512, 1024, 512, 512, 0);
        gemm_k<2,3,128><<<dim3(4,128), blk, 0, stream>>>(f_h2, f_g1, f_wg, bsi, bsig,
            f_h1, nullptr, nullptr, 0, 512, 1024, 512, 512, 0);

        gru32_k<false><<<dim3(32), dim3(384), 0, stream>>>(f_gi, Whh, f_h2, cw,
            f_hbuf, flags, 0, SEQ, SEQ);

        for (int pass = 0; pass < 2; ++pass) {
            const float* gptr = pass ? f_h1 : f_g1;
            int          cwi  = pass ? 1 : 2;
            for (int c = 0; c < MROWS/CH; ++c) {
                int r0 = c * CH;
                dim3 gIN(8, CH/128), gXP(1, CH/128), gDT(8, CH/128), gOUT(4, CH/128);
                dim3 gEL(CH/1024, 8);
                if (pass == 0) {
                    const float* Ax = x + (size_t)r0*512;
                    gemm_k<0,0,128><<<gIN, blk, 0, stream>>>(Ax, nullptr, ipW, nullptr, nullptr,
                        f_xiy, nullptr, nullptr, 0, 1024, 512, 512, 1024, 0);
                    gemm_k<0,0,128><<<gIN, blk, 0, stream>>>(Ax, nullptr, ipW + (size_t)1024*512, nullptr, nullptr,
                        f_z, nullptr, nullptr, 0, 1024, 512, 512, 1024, 0);
                } else {
                    gemm_k<3,0,128><<<gIN, blk, 0, stream>>>(x, nullptr, ipW, nullptr, nullptr,
                        f_xiy, nullptr, nullptr, 0, 1024, 512, 512, 1024, r0);
                    gemm_k<3,0,128><<<gIN, blk, 0, stream>>>(x, nullptr, ipW + (size_t)1024*512, nullptr, nullptr,
                        f_z, nullptr, nullptr, 0, 1024, 512, 512, 1024, r0);
                }
                dwconv4_k<<<gEL, dim3(128), 0, stream>>>(f_xiy, cw4, cb4);
                gemm_k<0,0,64><<<gXP, blk, 0, stream>>>(f_xiy, nullptr, xpW, nullptr, nullptr,
                    f_proj, nullptr, nullptr, 0, 64, 1024, 1024, 64, 0);
                gemm_k<0,4,128><<<gDT, blk, 0, stream>>>(f_proj, nullptr, dtW, dtb, nullptr,
                    f_dtc, nullptr, nullptr, 0, 1024, 32, 64, 1024, 0);
                scan_k<<<gEL, dim3(128), 0, stream>>>(f_dtc, f_xiy, f_z, f_proj, Alog, Dpf);
                gemm_k<0,5,128><<<gOUT, blk, 0, stream>>>(f_xiy, nullptr, opW, nullptr, nullptr,
                    f_h2 + (size_t)r0*512, gptr + (size_t)r0*512, cw, cwi, 512, 1024, 1024, 512, 0);
            }
        }

        gemm_k<0,1,128><<<dim3(4,128), blk, 0, stream>>>(f_h2, nullptr, Wp, bp, nullptr,
            (float*)d_out, nullptr, nullptr, 0, 512, 512, 512, 512, 0);
    } else {
        // ============ Tier C: bf16 gates + chunked GRU (~85 MB) =============
        float* f_t1   = ws;                          // 32 MB fp32 multi-use
        float* f_G1   = ws + (size_t)BUFF;           // bf16 h1n [16384][512]
        float* f_G2   = ws + (size_t)BUFF + 4194304; // bf16 h2n
        float* f_GI   = ws + (size_t)BUFF + 8388608; // bf16 gi chunk [4096][1536]
        float* f_wconv= f_GI + 3145728;
        float* f_wg   = f_wconv + 786432;
        float* f_hbuf = f_wg + 524288;
        int*   flags  = (int*)(f_hbuf + 16384);
        float* f_acc  = (float*)d_out;               // acc lives in d_out
        const int CH  = 2048;
        float* f_xiy  = f_t1;
        float* f_z    = f_xiy + (size_t)CH*1024;
        float* f_dtc  = f_z   + (size_t)CH*1024;
        float* f_proj = f_dtc + (size_t)CH*1024;

        repack_wconv_k <<<dim3(3072), blk, 0, stream>>>(Wc, f_wconv);
        repack_wgates_k<<<dim3(2048), blk, 0, stream>>>(Wsi, Wsig, f_wg);

        // h1raw -> T1 ; G1 = bf16 gates(h1raw)
        gemm_k<0,2,128><<<dim3(4,128), blk, 0, stream>>>(x, nullptr, W1, b1, nullptr,
            f_t1, x, nullptr, 0, 512, 512, 512, 512, 0);
        gemm_k<2,9,128><<<dim3(4,128), blk, 0, stream>>>(f_t1, f_t1, f_wg, bsi, bsig,
            f_G1, nullptr, nullptr, 0, 512, 1024, 512, 512, 0);
        // h2raw -> T1 ; G2 = bf16( silu(h2raw)@Wsi + sigmoid(bf16 G1)@Wsig + b )
        gemm_k<3,6,128><<<dim3(4,128), blk, 0, stream>>>(x, nullptr, W2, b2, nullptr,
            f_t1, x, nullptr, 0, 512, 512, 512, 512, 0);
        gemm_k<5,9,128><<<dim3(4,128), blk, 0, stream>>>(f_t1, f_G1, f_wg, bsi, bsig,
            f_G2, nullptr, nullptr, 0, 512, 1024, 512, 512, 0);
        // g1 -> T1
        gemm_k<1,1,128><<<dim3(4,128), blk, 0, stream>>>(x, nullptr, f_wconv, bc, nullptr,
            f_t1, nullptr, nullptr, 0, 512, 1536, 512, 512, 0);

        // chunked GRU: per 256-step chunk, gi_c (bf16) then gru steps
        for (int tc = 0; tc < 4; ++tc) {
            int t0 = tc * 256;
            gemm_k<4,8,128><<<dim3(12,32), blk, 0, stream>>>(f_t1, nullptr, Wih, nullptr, nullptr,
                f_GI, nullptr, nullptr, 0, 1536, 512, 512, 1536, t0);
            gru32_k<true><<<dim3(32), dim3(384), 0, stream>>>(f_GI, Whh, f_acc, cw,
                f_hbuf, flags, t0, t0 + 256, 256);
        }

        // mamba passes (chunk bufs overlay T1; gates read bf16 via EPI 7)
        for (int pass = 0; pass < 2; ++pass) {
            const float* gB = pass ? f_G2 : f_G1;
            int          cwi = pass ? 1 : 2;
            for (int c = 0; c < MROWS/CH; ++c) {
                int r0 = c * CH;
                dim3 gIN(8, CH/128), gXP(1, CH/128), gDT(8, CH/128), gOUT(4, CH/128);
                dim3 gEL(CH/1024, 8);
                if (pass == 0) {
                    const float* Ax = x + (size_t)r0*512;
                    gemm_k<0,0,128><<<gIN, blk, 0, stream>>>(Ax, nullptr, ipW, nullptr, nullptr,
                        f_xiy, nullptr, nullptr, 0, 1024, 512, 512, 1024, 0);
                    gemm_k<0,0,128><<<gIN, blk, 0, stream>>>(Ax, nullptr, ipW + (size_t)1024*512, nullptr, nullptr,
                        f_z, nullptr, nullptr, 0, 1024, 512, 512, 1024, 0);
                } else {
                    gemm_k<3,0,128><<<gIN, blk, 0, stream>>>(x, nullptr, ipW, nullptr, nullptr,
                        f_xiy, nullptr, nullptr, 0, 1024, 512, 512, 1024, r0);
                    gemm_k<3,0,128><<<gIN, blk, 0, stream>>>(x, nullptr, ipW + (size_t)1024*512, nullptr, nullptr,
                        f_z, nullptr, nullptr, 0, 1024, 512, 512, 1024, r0);
                }
                dwconv4_k<<<gEL, dim3(128), 0, stream>>>(f_xiy, cw4, cb4);
                gemm_k<0,0,64><<<gXP, blk, 0, stream>>>(f_xiy, nullptr, xpW, nullptr, nullptr,
                    f_proj, nullptr, nullptr, 0, 64, 1024, 1024, 64, 0);
                gemm_k<0,4,128><<<gDT, blk, 0, stream>>>(f_proj, nullptr, dtW, dtb, nullptr,
                    f_dtc, nullptr, nullptr, 0, 1024, 32, 64, 1024, 0);
                scan_k<<<gEL, dim3(128), 0, stream>>>(f_dtc, f_xiy, f_z, f_proj, Alog, Dpf);
                const float* gchunk = (const float*)((const __hip_bfloat16*)gB + (size_t)r0*512);
                gemm_k<0,7,128><<<gOUT, blk, 0, stream>>>(f_xiy, nullptr, opW, nullptr, nullptr,
                    f_acc + (size_t)r0*512, gchunk, cw, cwi, 512, 1024, 1024, 512, 0);
            }
        }

        // final = acc(d_out) @ Wp^T + bp -> T1 ; copy back to d_out
        gemm_k<0,1,128><<<dim3(4,128), blk, 0, stream>>>(f_acc, nullptr, Wp, bp, nullptr,
            f_t1, nullptr, nullptr, 0, 512, 512, 512, 512, 0);
        hipMemcpyAsync(d_out, f_t1, (size_t)out_size * sizeof(float),
                       hipMemcpyDeviceToDevice, stream);
    }
}